// Round 1
// baseline (643.424 us; speedup 1.0000x reference)
//
#include <hip/hip_runtime.h>
#include <hip/hip_bf16.h>
#include <math.h>

#define NTOK 16384
#define DDIM 1024
#define HALF 512
#define SUB  512
#define KDIM 512
#define TOPK 8
#define NCAND 16
#define VDIM 128
#define TM 16
#define KC 16
#define SC_PAD 514   // KC rows of SUB floats, padded stride to kill write conflicts

// ---------------------------------------------------------------------------
// Kernel 1: per block = 16 tokens x one codebook half.
// Phase 1: register-tiled fp32 GEMM (thread tile 4 tokens x 8 cols).
// Phase 2: per-wave coarse top-16 on fp32 scores, fp64 rescore of the 16
//          candidates (matches a float64 numpy reference's ordering), rank,
//          emit top-8 (idx, val) per (token, half).
// ---------------------------------------------------------------------------
__global__ __launch_bounds__(256)
void score_topk_kernel(const float* __restrict__ query,
                       const float* __restrict__ cb1,
                       const float* __restrict__ cb2,
                       int*   __restrict__ tk_idx,   // [NTOK][2][TOPK]
                       float* __restrict__ tk_val)   // [NTOK][2][TOPK]
{
    __shared__ float sQ[TM][KC];
    __shared__ float sC[KC * SC_PAD];   // reused as scores sS[TM][SUB] in phase 2

    const int tid  = threadIdx.x;
    const int half = blockIdx.y;
    const int tok0 = blockIdx.x * TM;
    const float* __restrict__ cb = half ? cb2 : cb1;
    const int qoff = half * HALF;

    const int cg = tid & 63;   // lane: column group (cols cg + 64*u)
    const int tg = tid >> 6;   // wave id: token group (tokens tg*4 + v)

    float acc[4][8];
    #pragma unroll
    for (int v = 0; v < 4; v++)
        #pragma unroll
        for (int u = 0; u < 8; u++) acc[v][u] = 0.f;

    for (int k0 = 0; k0 < KDIM; k0 += KC) {
        // stage Q tile: 16 tokens x KC
        {
            int t = tid >> 4, kk = tid & 15;
            sQ[t][kk] = query[(size_t)(tok0 + t) * DDIM + qoff + k0 + kk];
        }
        // stage codebook tile transposed: sC[kk][c]
        {
            int c0 = tid >> 2, k4 = (tid & 3) * 4;
            #pragma unroll
            for (int i = 0; i < 8; i++) {
                int c = c0 + i * 64;
                float4 vv = *(const float4*)&cb[(size_t)c * KDIM + k0 + k4];
                sC[(k4 + 0) * SC_PAD + c] = vv.x;
                sC[(k4 + 1) * SC_PAD + c] = vv.y;
                sC[(k4 + 2) * SC_PAD + c] = vv.z;
                sC[(k4 + 3) * SC_PAD + c] = vv.w;
            }
        }
        __syncthreads();

        #pragma unroll
        for (int kk = 0; kk < KC; kk += 4) {
            float4 qv[4];
            #pragma unroll
            for (int v = 0; v < 4; v++)
                qv[v] = *(const float4*)&sQ[tg * 4 + v][kk];
            #pragma unroll
            for (int s = 0; s < 4; s++) {
                float cv[8];
                #pragma unroll
                for (int u = 0; u < 8; u++)
                    cv[u] = sC[(kk + s) * SC_PAD + cg + 64 * u];
                #pragma unroll
                for (int v = 0; v < 4; v++) {
                    float q = (s == 0) ? qv[v].x : (s == 1) ? qv[v].y
                            : (s == 2) ? qv[v].z : qv[v].w;
                    #pragma unroll
                    for (int u = 0; u < 8; u++)
                        acc[v][u] = fmaf(q, cv[u], acc[v][u]);
                }
            }
        }
        __syncthreads();
    }

    // dump scores to LDS (reuse sC): sS[t][c]
    float* sS = sC;
    #pragma unroll
    for (int v = 0; v < 4; v++)
        #pragma unroll
        for (int u = 0; u < 8; u++)
            sS[(tg * 4 + v) * SUB + cg + 64 * u] = acc[v][u];
    __syncthreads();

    // ---- phase 2: per wave, 4 tokens ----
    const int lane = cg;
    for (int v = 0; v < 4; v++) {
        const int t   = tg * 4 + v;
        const int tok = tok0 + t;

        float sv[8];
        #pragma unroll
        for (int j = 0; j < 8; j++) sv[j] = sS[t * SUB + lane + 64 * j];

        // coarse top-16 via 16 x wave-argmax (tie -> lower index, like lax.top_k)
        int cand[NCAND];
        #pragma unroll
        for (int r = 0; r < NCAND; r++) {
            float bv = sv[0]; int bj = 0;
            #pragma unroll
            for (int j = 1; j < 8; j++) if (sv[j] > bv) { bv = sv[j]; bj = j; }
            int bidx = lane + 64 * bj;
            #pragma unroll
            for (int off = 32; off > 0; off >>= 1) {
                float ov = __shfl_xor(bv, off);
                int   oi = __shfl_xor(bidx, off);
                if (ov > bv || (ov == bv && oi < bidx)) { bv = ov; bidx = oi; }
            }
            cand[r] = bidx;                 // uniform across wave
            int jj = bidx >> 6;
            if ((bidx & 63) == lane) {
                #pragma unroll
                for (int j = 0; j < 8; j++) if (j == jj) sv[j] = -INFINITY;
            }
        }

        // fp64 rescore of the 16 candidates
        double qd[8];
        #pragma unroll
        for (int j = 0; j < 8; j++)
            qd[j] = (double)query[(size_t)tok * DDIM + qoff + lane + 64 * j];

        double rv[NCAND];
        #pragma unroll
        for (int r = 0; r < NCAND; r++) {
            const float* __restrict__ crow = &cb[(size_t)cand[r] * KDIM];
            double a = 0.0;
            #pragma unroll
            for (int j = 0; j < 8; j++)
                a = fma(qd[j], (double)crow[lane + 64 * j], a);
            #pragma unroll
            for (int off = 32; off > 0; off >>= 1)
                a += __shfl_xor(a, off);
            rv[r] = a;                      // lane 0's copy is authoritative
        }

        // rank (value desc, tie -> lower index) and emit top-8 from lane 0
        if (lane == 0) {
            #pragma unroll
            for (int r = 0; r < NCAND; r++) {
                int rk = 0;
                #pragma unroll
                for (int m = 0; m < NCAND; m++)
                    if (rv[m] > rv[r] || (rv[m] == rv[r] && cand[m] < cand[r])) rk++;
                if (rk < TOPK) {
                    tk_idx[((size_t)tok * 2 + half) * TOPK + rk] = cand[r];
                    tk_val[((size_t)tok * 2 + half) * TOPK + rk] = (float)rv[r];
                }
            }
        }
    }
}

// ---------------------------------------------------------------------------
// Kernel 2: one wave per token. softmax(8)x2 -> 64 weighted value rows.
// ---------------------------------------------------------------------------
__global__ __launch_bounds__(256)
void gather_kernel(const float* __restrict__ values,
                   const int*   __restrict__ tk_idx,
                   const float* __restrict__ tk_val,
                   float* __restrict__ out)
{
    const int tid  = threadIdx.x;
    const int lane = tid & 63;
    const int tok  = blockIdx.x * 4 + (tid >> 6);

    const int b1 = (tok * 2 + 0) * TOPK;
    const int b2 = (tok * 2 + 1) * TOPK;

    float v1[8], v2[8]; int i1[8], i2[8];
    #pragma unroll
    for (int j = 0; j < 8; j++) {
        i1[j] = tk_idx[b1 + j]; v1[j] = tk_val[b1 + j];
        i2[j] = tk_idx[b2 + j]; v2[j] = tk_val[b2 + j];
    }

    float m1 = v1[0], m2 = v2[0];
    #pragma unroll
    for (int j = 1; j < 8; j++) { m1 = fmaxf(m1, v1[j]); m2 = fmaxf(m2, v2[j]); }

    float w1[8], w2[8], s1 = 0.f, s2 = 0.f;
    #pragma unroll
    for (int j = 0; j < 8; j++) {
        w1[j] = expf(v1[j] - m1); s1 += w1[j];
        w2[j] = expf(v2[j] - m2); s2 += w2[j];
    }
    const float inv1 = 1.f / s1, inv2 = 1.f / s2;
    #pragma unroll
    for (int j = 0; j < 8; j++) { w1[j] *= inv1; w2[j] *= inv2; }

    float2 acc = make_float2(0.f, 0.f);
    #pragma unroll
    for (int i = 0; i < 8; i++) {
        const int rb = i1[i] * SUB;
        const float wi = w1[i];
        #pragma unroll
        for (int j = 0; j < 8; j++) {
            const float w = wi * w2[j];
            const float* __restrict__ row = values + (size_t)(rb + i2[j]) * VDIM;
            float2 tv = *(const float2*)&row[lane * 2];
            acc.x = fmaf(w, tv.x, acc.x);
            acc.y = fmaf(w, tv.y, acc.y);
        }
    }
    *(float2*)&out[(size_t)tok * VDIM + lane * 2] = acc;
}

extern "C" void kernel_launch(void* const* d_in, const int* in_sizes, int n_in,
                              void* d_out, int out_size, void* d_ws, size_t ws_size,
                              hipStream_t stream) {
    const float* query  = (const float*)d_in[0];
    const float* cb1    = (const float*)d_in[1];
    const float* cb2    = (const float*)d_in[2];
    const float* values = (const float*)d_in[3];
    float* out = (float*)d_out;

    int*   tk_idx = (int*)d_ws;
    float* tk_val = (float*)((char*)d_ws + (size_t)NTOK * 2 * TOPK * sizeof(int));

    dim3 g1(NTOK / TM, 2);
    score_topk_kernel<<<g1, 256, 0, stream>>>(query, cb1, cb2, tk_idx, tk_val);
    gather_kernel<<<NTOK / 4, 256, 0, stream>>>(values, tk_idx, tk_val, out);
}

// Round 2
// 465.999 us; speedup vs baseline: 1.3807x; 1.3807x over previous
//
#include <hip/hip_runtime.h>
#include <hip/hip_bf16.h>
#include <math.h>

#define NTOK 16384
#define DDIM 1024
#define HALF 512
#define SUB  512
#define KDIM 512
#define TOPK 8
#define NCAND 16
#define VDIM 128
#define TMB 32          // tokens per block (score kernel)
#define KC2 32          // K chunk for B staging

typedef __attribute__((ext_vector_type(8))) short bf16x8;
typedef __attribute__((ext_vector_type(4))) float f32x4;

static __device__ __forceinline__ unsigned short f2bf(float x) {
    union { float f; unsigned u; } v; v.f = x;
    unsigned r = v.u + 0x7FFF + ((v.u >> 16) & 1);   // RNE
    return (unsigned short)(r >> 16);
}

// ---------------------------------------------------------------------------
// Kernel 0: fp32 -> bf16 codebook conversion (both codebooks, 512x512 each)
// ---------------------------------------------------------------------------
__global__ __launch_bounds__(256)
void cvt_kernel(const float* __restrict__ c1, const float* __restrict__ c2,
                unsigned short* __restrict__ o1, unsigned short* __restrict__ o2)
{
    int i = (blockIdx.x * 256 + threadIdx.x) * 8;   // 256 blocks -> 524288 elems
    const float* s; unsigned short* d; int off;
    if (i < SUB * KDIM) { s = c1; d = o1; off = i; }
    else                { s = c2; d = o2; off = i - SUB * KDIM; }
    float4 a = *(const float4*)(s + off);
    float4 b = *(const float4*)(s + off + 4);
    unsigned short u[8] = { f2bf(a.x), f2bf(a.y), f2bf(a.z), f2bf(a.w),
                            f2bf(b.x), f2bf(b.y), f2bf(b.z), f2bf(b.w) };
    *(int4*)(d + off) = *(const int4*)u;
}

// ---------------------------------------------------------------------------
// Kernel 1: per block = 32 tokens x one half. 512 threads (8 waves).
// Phase 1: bf16 MFMA GEMM (wave tile 32 tok x 64 cols), coarse fp32 scores.
// Phase 2: coarse top-16 (wave-argmax) + fp64 rescore -> exact top-8.
// ---------------------------------------------------------------------------
__global__ __launch_bounds__(512, 4)
void score_topk_mfma(const float* __restrict__ query,
                     const float* __restrict__ cb1f,
                     const float* __restrict__ cb2f,
                     const unsigned short* __restrict__ cbb1,
                     const unsigned short* __restrict__ cbb2,
                     int*   __restrict__ tk_idx,
                     float* __restrict__ tk_val)
{
    __shared__ char smem[65536];
    char* sA = smem;            // bf16 [32][512], swizzled: row*1024 + (colb ^ ((row&7)<<4))
    char* sB = smem + 32768;    // bf16 [512][32], swizzled: (n*64 + o) ^ ((n&7)<<4)
    float* sS = (float*)smem;   // phase 2: fp32 scores [32][512] (overlays sA+sB)

    const int tid  = threadIdx.x;
    const int half = blockIdx.y;
    const int tok0 = blockIdx.x * TMB;
    const unsigned short* __restrict__ cbb = half ? cbb2 : cbb1;
    const float* __restrict__ cbf = half ? cb2f : cb1f;
    const int qoff = half * HALF;

    const int lane = tid & 63;
    const int wid  = tid >> 6;          // 0..7
    const int l15  = lane & 15;
    const int lh   = lane >> 4;         // 0..3
    const int l7   = lane & 7;

    // ---- stage A: query tile fp32 -> bf16, swizzled ----
    #pragma unroll
    for (int i = 0; i < 4; i++) {
        int c   = i * 512 + tid;        // 0..2047 16B-chunks
        int row = c >> 6;               // 64 chunks per row
        int b8  = c & 63;
        const float* src = query + (size_t)(tok0 + row) * DDIM + qoff + b8 * 8;
        float4 f0 = *(const float4*)(src);
        float4 f1 = *(const float4*)(src + 4);
        unsigned short u[8] = { f2bf(f0.x), f2bf(f0.y), f2bf(f0.z), f2bf(f0.w),
                                f2bf(f1.x), f2bf(f1.y), f2bf(f1.z), f2bf(f1.w) };
        int boff = row * 1024 + ((b8 * 16) ^ ((row & 7) << 4));
        *(int4*)(sA + boff) = *(const int4*)u;
    }

    // ---- prefetch + write B chunk 0 ----
    int4 pf[4];
    #pragma unroll
    for (int i = 0; i < 4; i++) {
        int c = i * 512 + tid; int n = c >> 2, c4 = c & 3;
        pf[i] = *(const int4*)((const char*)cbb + (size_t)n * 1024 + c4 * 16);
    }
    #pragma unroll
    for (int i = 0; i < 4; i++) {
        int c = i * 512 + tid; int n = c >> 2, c4 = c & 3;
        *(int4*)(sB + ((n * 64 + c4 * 16) ^ ((n & 7) << 4))) = pf[i];
    }
    __syncthreads();

    f32x4 acc[2][4];
    #pragma unroll
    for (int tf = 0; tf < 2; tf++)
        #pragma unroll
        for (int nf = 0; nf < 4; nf++)
            acc[tf][nf] = (f32x4){0.f, 0.f, 0.f, 0.f};

    for (int cc = 0; cc < 16; cc++) {
        const int k0b = cc * 64;                       // k0 * 2 bytes
        if (cc < 15) {
            #pragma unroll
            for (int i = 0; i < 4; i++) {
                int c = i * 512 + tid; int n = c >> 2, c4 = c & 3;
                pf[i] = *(const int4*)((const char*)cbb + (size_t)n * 1024 + k0b + 64 + c4 * 16);
            }
        }
        bf16x8 a[2], b[4];
        #pragma unroll
        for (int tf = 0; tf < 2; tf++)
            a[tf] = *(const bf16x8*)(sA + (tf * 16 + l15) * 1024
                                        + ((k0b + lh * 16) ^ (l7 << 4)));
        #pragma unroll
        for (int nf = 0; nf < 4; nf++) {
            int n = wid * 64 + nf * 16 + l15;
            b[nf] = *(const bf16x8*)(sB + ((n * 64 + lh * 16) ^ (l7 << 4)));
        }
        #pragma unroll
        for (int tf = 0; tf < 2; tf++)
            #pragma unroll
            for (int nf = 0; nf < 4; nf++)
                acc[tf][nf] = __builtin_amdgcn_mfma_f32_16x16x32_bf16(
                                  a[tf], b[nf], acc[tf][nf], 0, 0, 0);
        __syncthreads();
        if (cc < 15) {
            #pragma unroll
            for (int i = 0; i < 4; i++) {
                int c = i * 512 + tid; int n = c >> 2, c4 = c & 3;
                *(int4*)(sB + ((n * 64 + c4 * 16) ^ ((n & 7) << 4))) = pf[i];
            }
        }
        __syncthreads();
    }

    // ---- dump coarse scores: C/D layout row=(lane>>4)*4+reg, col=lane&15 ----
    #pragma unroll
    for (int tf = 0; tf < 2; tf++)
        #pragma unroll
        for (int nf = 0; nf < 4; nf++)
            #pragma unroll
            for (int r = 0; r < 4; r++)
                sS[(tf * 16 + lh * 4 + r) * SUB + wid * 64 + nf * 16 + l15]
                    = acc[tf][nf][r];
    __syncthreads();

    // ---- phase 2: per wave, 4 tokens ----
    for (int v = 0; v < 4; v++) {
        const int t   = wid * 4 + v;
        const int tok = tok0 + t;

        float sv[8];
        #pragma unroll
        for (int j = 0; j < 8; j++) sv[j] = sS[t * SUB + lane + 64 * j];

        // coarse top-16 via 16 x wave-argmax (tie -> lower index)
        int cand[NCAND];
        #pragma unroll
        for (int r = 0; r < NCAND; r++) {
            float bv = sv[0]; int bj = 0;
            #pragma unroll
            for (int j = 1; j < 8; j++) if (sv[j] > bv) { bv = sv[j]; bj = j; }
            int bidx = lane + 64 * bj;
            #pragma unroll
            for (int off = 32; off > 0; off >>= 1) {
                float ov = __shfl_xor(bv, off);
                int   oi = __shfl_xor(bidx, off);
                if (ov > bv || (ov == bv && oi < bidx)) { bv = ov; bidx = oi; }
            }
            cand[r] = bidx;
            int jj = bidx >> 6;
            if ((bidx & 63) == lane) {
                #pragma unroll
                for (int j = 0; j < 8; j++) if (j == jj) sv[j] = -INFINITY;
            }
        }

        // fp64 rescore of the 16 candidates (exact ordering + exact logits)
        double qd[8];
        #pragma unroll
        for (int j = 0; j < 8; j++)
            qd[j] = (double)query[(size_t)tok * DDIM + qoff + lane + 64 * j];

        double rv[NCAND];
        #pragma unroll
        for (int r = 0; r < NCAND; r++) {
            const float* __restrict__ crow = &cbf[(size_t)cand[r] * KDIM];
            double a = 0.0;
            #pragma unroll
            for (int j = 0; j < 8; j++)
                a = fma(qd[j], (double)crow[lane + 64 * j], a);
            #pragma unroll
            for (int off = 32; off > 0; off >>= 1)
                a += __shfl_xor(a, off);
            rv[r] = a;
        }

        if (lane == 0) {
            #pragma unroll
            for (int r = 0; r < NCAND; r++) {
                int rk = 0;
                #pragma unroll
                for (int m = 0; m < NCAND; m++)
                    if (rv[m] > rv[r] || (rv[m] == rv[r] && cand[m] < cand[r])) rk++;
                if (rk < TOPK) {
                    tk_idx[((size_t)tok * 2 + half) * TOPK + rk] = cand[r];
                    tk_val[((size_t)tok * 2 + half) * TOPK + rk] = (float)rv[r];
                }
            }
        }
    }
}

// ---------------------------------------------------------------------------
// Kernel 2: one wave per token. softmax(8)x2 -> 64 weighted value rows.
// ---------------------------------------------------------------------------
__global__ __launch_bounds__(256)
void gather_kernel(const float* __restrict__ values,
                   const int*   __restrict__ tk_idx,
                   const float* __restrict__ tk_val,
                   float* __restrict__ out)
{
    const int tid  = threadIdx.x;
    const int lane = tid & 63;
    const int tok  = blockIdx.x * 4 + (tid >> 6);

    const int b1 = (tok * 2 + 0) * TOPK;
    const int b2 = (tok * 2 + 1) * TOPK;

    float v1[8], v2[8]; int i1[8], i2[8];
    #pragma unroll
    for (int j = 0; j < 8; j++) {
        i1[j] = tk_idx[b1 + j]; v1[j] = tk_val[b1 + j];
        i2[j] = tk_idx[b2 + j]; v2[j] = tk_val[b2 + j];
    }

    float m1 = v1[0], m2 = v2[0];
    #pragma unroll
    for (int j = 1; j < 8; j++) { m1 = fmaxf(m1, v1[j]); m2 = fmaxf(m2, v2[j]); }

    float w1[8], w2[8], s1 = 0.f, s2 = 0.f;
    #pragma unroll
    for (int j = 0; j < 8; j++) {
        w1[j] = expf(v1[j] - m1); s1 += w1[j];
        w2[j] = expf(v2[j] - m2); s2 += w2[j];
    }
    const float inv1 = 1.f / s1, inv2 = 1.f / s2;
    #pragma unroll
    for (int j = 0; j < 8; j++) { w1[j] *= inv1; w2[j] *= inv2; }

    float2 acc = make_float2(0.f, 0.f);
    #pragma unroll
    for (int i = 0; i < 8; i++) {
        const int rb = i1[i] * SUB;
        const float wi = w1[i];
        #pragma unroll
        for (int j = 0; j < 8; j++) {
            const float w = wi * w2[j];
            const float* __restrict__ row = values + (size_t)(rb + i2[j]) * VDIM;
            float2 tv = *(const float2*)&row[lane * 2];
            acc.x = fmaf(w, tv.x, acc.x);
            acc.y = fmaf(w, tv.y, acc.y);
        }
    }
    *(float2*)&out[(size_t)tok * VDIM + lane * 2] = acc;
}

extern "C" void kernel_launch(void* const* d_in, const int* in_sizes, int n_in,
                              void* d_out, int out_size, void* d_ws, size_t ws_size,
                              hipStream_t stream) {
    const float* query  = (const float*)d_in[0];
    const float* cb1    = (const float*)d_in[1];
    const float* cb2    = (const float*)d_in[2];
    const float* values = (const float*)d_in[3];
    float* out = (float*)d_out;

    char* ws = (char*)d_ws;
    int*            tk_idx = (int*)ws;                                 // 1 MB
    float*          tk_val = (float*)(ws + (1u << 20));                // 1 MB
    unsigned short* cbb1   = (unsigned short*)(ws + (2u << 20));       // 512 KB
    unsigned short* cbb2   = (unsigned short*)(ws + (2u << 20) + (512u << 10));

    cvt_kernel<<<SUB * KDIM * 2 / (256 * 8), 256, 0, stream>>>(cb1, cb2, cbb1, cbb2);
    dim3 g1(NTOK / TMB, 2);
    score_topk_mfma<<<g1, 512, 0, stream>>>(query, cb1, cb2, cbb1, cbb2, tk_idx, tk_val);
    gather_kernel<<<NTOK / 4, 256, 0, stream>>>(values, tk_idx, tk_val, out);
}

// Round 3
// 383.808 us; speedup vs baseline: 1.6764x; 1.2141x over previous
//
#include <hip/hip_runtime.h>
#include <hip/hip_bf16.h>
#include <math.h>

#define NTOK 16384
#define DDIM 1024
#define HALF 512
#define SUB  512
#define KDIM 512
#define TOPK 8
#define NCAND 16
#define VDIM 128
#define TMB 32

typedef __attribute__((ext_vector_type(8))) short bf16x8;
typedef __attribute__((ext_vector_type(4))) float f32x4;

static __device__ __forceinline__ unsigned short f2bf(float x) {
    union { float f; unsigned u; } v; v.f = x;
    unsigned r = v.u + 0x7FFF + ((v.u >> 16) & 1);   // RNE
    return (unsigned short)(r >> 16);
}

static __device__ __forceinline__ void split_bf(float x, unsigned short& h, unsigned short& l) {
    h = f2bf(x);
    union { unsigned u; float f; } hv; hv.u = ((unsigned)h) << 16;
    l = f2bf(x - hv.f);
}

// ---------------------------------------------------------------------------
// Kernel 0: fp32 codebooks -> bf16 hi + bf16 lo arrays (row-major, as source)
// ---------------------------------------------------------------------------
__global__ __launch_bounds__(256)
void cvt_kernel(const float* __restrict__ c1, const float* __restrict__ c2,
                unsigned short* __restrict__ h1, unsigned short* __restrict__ l1,
                unsigned short* __restrict__ h2, unsigned short* __restrict__ l2)
{
    int i = (blockIdx.x * 256 + threadIdx.x) * 8;
    const float* s; unsigned short *dh, *dl; int off;
    if (i < SUB * KDIM) { s = c1; dh = h1; dl = l1; off = i; }
    else                { s = c2; dh = h2; dl = l2; off = i - SUB * KDIM; }
    float4 a = *(const float4*)(s + off);
    float4 b = *(const float4*)(s + off + 4);
    unsigned short hh[8], ll[8];
    split_bf(a.x, hh[0], ll[0]); split_bf(a.y, hh[1], ll[1]);
    split_bf(a.z, hh[2], ll[2]); split_bf(a.w, hh[3], ll[3]);
    split_bf(b.x, hh[4], ll[4]); split_bf(b.y, hh[5], ll[5]);
    split_bf(b.z, hh[6], ll[6]); split_bf(b.w, hh[7], ll[7]);
    *(int4*)(dh + off) = *(const int4*)hh;
    *(int4*)(dl + off) = *(const int4*)ll;
}

// ---------------------------------------------------------------------------
// Kernel 1: per block = 32 tokens x one half. 512 threads (8 waves).
// Phase 1: split-bf16 3-pass MFMA GEMM -> fp32-accurate scores (err ~1e-5).
// Phase 2: ballot binary-search top-8 (fast, certainty-gated) with R2's
//          argmax+fp64-rescore slow path for ambiguous tokens (~0.3%).
// ---------------------------------------------------------------------------
__global__ __launch_bounds__(512)
void score_topk_mfma(const float* __restrict__ query,
                     const float* __restrict__ cb1f,
                     const float* __restrict__ cb2f,
                     const unsigned short* __restrict__ cbh1,
                     const unsigned short* __restrict__ cbl1,
                     const unsigned short* __restrict__ cbh2,
                     const unsigned short* __restrict__ cbl2,
                     int*   __restrict__ tk_idx,
                     float* __restrict__ tk_val)
{
    __shared__ char smem[131072];
    char* sAh = smem;            // bf16 [32][512] swizzled
    char* sAl = smem + 32768;
    char* sBh = smem + 65536;    // bf16 [512 cands][32 k] swizzled, per chunk
    char* sBl = smem + 98304;
    float* sS = (float*)smem;    // phase 2: fp32 [32][512] (overlays A+B)

    const int tid  = threadIdx.x;
    const int half = blockIdx.y;
    const int tok0 = blockIdx.x * TMB;
    const unsigned short* __restrict__ cbh = half ? cbh2 : cbh1;
    const unsigned short* __restrict__ cbl = half ? cbl2 : cbl1;
    const float* __restrict__ cbf = half ? cb2f : cb1f;
    const int qoff = half * HALF;

    const int lane = tid & 63;
    const int wid  = tid >> 6;
    const int l15  = lane & 15;
    const int lh   = lane >> 4;
    const int l7   = lane & 7;

    // ---- stage A: query tile fp32 -> bf16 hi/lo, swizzled ----
    #pragma unroll
    for (int i = 0; i < 4; i++) {
        int c   = i * 512 + tid;
        int row = c >> 6;
        int b8  = c & 63;
        const float* src = query + (size_t)(tok0 + row) * DDIM + qoff + b8 * 8;
        float4 f0 = *(const float4*)(src);
        float4 f1 = *(const float4*)(src + 4);
        unsigned short hh[8], ll[8];
        split_bf(f0.x, hh[0], ll[0]); split_bf(f0.y, hh[1], ll[1]);
        split_bf(f0.z, hh[2], ll[2]); split_bf(f0.w, hh[3], ll[3]);
        split_bf(f1.x, hh[4], ll[4]); split_bf(f1.y, hh[5], ll[5]);
        split_bf(f1.z, hh[6], ll[6]); split_bf(f1.w, hh[7], ll[7]);
        int boff = row * 1024 + ((b8 * 16) ^ ((row & 7) << 4));
        *(int4*)(sAh + boff) = *(const int4*)hh;
        *(int4*)(sAl + boff) = *(const int4*)ll;
    }

    // ---- prefetch + write B chunk 0 ----
    int4 pfh[4], pfl[4];
    #pragma unroll
    for (int i = 0; i < 4; i++) {
        int c = i * 512 + tid; int n = c >> 2, c4 = c & 3;
        pfh[i] = *(const int4*)((const char*)cbh + (size_t)n * 1024 + c4 * 16);
        pfl[i] = *(const int4*)((const char*)cbl + (size_t)n * 1024 + c4 * 16);
    }
    #pragma unroll
    for (int i = 0; i < 4; i++) {
        int c = i * 512 + tid; int n = c >> 2, c4 = c & 3;
        int boff = (n * 64 + c4 * 16) ^ ((n & 7) << 4);
        *(int4*)(sBh + boff) = pfh[i];
        *(int4*)(sBl + boff) = pfl[i];
    }
    __syncthreads();

    f32x4 acc[2][4];
    #pragma unroll
    for (int tf = 0; tf < 2; tf++)
        #pragma unroll
        for (int nf = 0; nf < 4; nf++)
            acc[tf][nf] = (f32x4){0.f, 0.f, 0.f, 0.f};

    for (int cc = 0; cc < 16; cc++) {
        const int k0b = cc * 64;
        if (cc < 15) {
            #pragma unroll
            for (int i = 0; i < 4; i++) {
                int c = i * 512 + tid; int n = c >> 2, c4 = c & 3;
                size_t g = (size_t)n * 1024 + k0b + 64 + c4 * 16;
                pfh[i] = *(const int4*)((const char*)cbh + g);
                pfl[i] = *(const int4*)((const char*)cbl + g);
            }
        }
        bf16x8 ah[2], al[2], bh[4], bl[4];
        #pragma unroll
        for (int tf = 0; tf < 2; tf++) {
            int aoff = (tf * 16 + l15) * 1024 + ((k0b + lh * 16) ^ (l7 << 4));
            ah[tf] = *(const bf16x8*)(sAh + aoff);
            al[tf] = *(const bf16x8*)(sAl + aoff);
        }
        #pragma unroll
        for (int nf = 0; nf < 4; nf++) {
            int n = wid * 64 + nf * 16 + l15;
            int boff = (n * 64 + lh * 16) ^ ((n & 7) << 4);
            bh[nf] = *(const bf16x8*)(sBh + boff);
            bl[nf] = *(const bf16x8*)(sBl + boff);
        }
        #pragma unroll
        for (int tf = 0; tf < 2; tf++)
            #pragma unroll
            for (int nf = 0; nf < 4; nf++) {
                acc[tf][nf] = __builtin_amdgcn_mfma_f32_16x16x32_bf16(ah[tf], bh[nf], acc[tf][nf], 0, 0, 0);
                acc[tf][nf] = __builtin_amdgcn_mfma_f32_16x16x32_bf16(ah[tf], bl[nf], acc[tf][nf], 0, 0, 0);
                acc[tf][nf] = __builtin_amdgcn_mfma_f32_16x16x32_bf16(al[tf], bh[nf], acc[tf][nf], 0, 0, 0);
            }
        __syncthreads();
        if (cc < 15) {
            #pragma unroll
            for (int i = 0; i < 4; i++) {
                int c = i * 512 + tid; int n = c >> 2, c4 = c & 3;
                int boff = (n * 64 + c4 * 16) ^ ((n & 7) << 4);
                *(int4*)(sBh + boff) = pfh[i];
                *(int4*)(sBl + boff) = pfl[i];
            }
        }
        __syncthreads();
    }

    // ---- dump scores (XOR hash kills the 4-way write conflict) ----
    #pragma unroll
    for (int tf = 0; tf < 2; tf++)
        #pragma unroll
        for (int nf = 0; nf < 4; nf++)
            #pragma unroll
            for (int r = 0; r < 4; r++) {
                int t = tf * 16 + lh * 4 + r;
                int c = wid * 64 + nf * 16 + l15;
                sS[t * SUB + (c ^ (lh << 3))] = acc[tf][nf][r];
            }
    __syncthreads();

    // ---- phase 2: per wave, 4 tokens ----
    const int hsh = (wid & 3) << 3;    // = ((t>>2)&3)<<3 for t = wid*4+v
    for (int v = 0; v < 4; v++) {
        const int t   = wid * 4 + v;
        const int tok = tok0 + t;

        float sv[8];
        #pragma unroll
        for (int j = 0; j < 8; j++) sv[j] = sS[t * SUB + ((lane + 64 * j) ^ hsh)];

        // wave max
        float m = sv[0];
        #pragma unroll
        for (int j = 1; j < 8; j++) m = fmaxf(m, sv[j]);
        #pragma unroll
        for (int off = 32; off > 0; off >>= 1) m = fmaxf(m, __shfl_xor(m, off));

        auto wave_cnt = [&](float tau) -> int {
            int c = 0;
            #pragma unroll
            for (int j = 0; j < 8; j++)
                c += __popcll(__ballot(sv[j] > tau));
            return c;
        };

        float lo = m - 3.0f, hi = m;
        while (wave_cnt(lo) < 9) lo -= 3.0f;      // never taken for this data
        for (int it = 0; it < 17; it++) {
            float mid = 0.5f * (lo + hi);
            if (wave_cnt(mid) >= 9) lo = mid; else hi = mid;
        }
        int ch = wave_cnt(hi);

        float v8 = 1e30f, v9 = -1e30f;
        #pragma unroll
        for (int j = 0; j < 8; j++) {
            bool sel = sv[j] > hi;
            v8 = sel ? fminf(v8, sv[j]) : v8;
            v9 = sel ? v9 : fmaxf(v9, sv[j]);
        }
        #pragma unroll
        for (int off = 32; off > 0; off >>= 1) {
            v8 = fminf(v8, __shfl_xor(v8, off));
            v9 = fmaxf(v9, __shfl_xor(v9, off));
        }

        if (ch == 8 && (v8 - v9) > 6e-5f) {
            // fast path: emit the certain top-8 set (order irrelevant)
            int base = 0;
            #pragma unroll
            for (int j = 0; j < 8; j++) {
                unsigned long long mk = __ballot(sv[j] > hi);
                if (sv[j] > hi) {
                    int pos = base + __popcll(mk & ((1ULL << lane) - 1ULL));
                    tk_idx[((size_t)tok * 2 + half) * TOPK + pos] = lane + 64 * j;
                    tk_val[((size_t)tok * 2 + half) * TOPK + pos] = sv[j];
                }
                base += __popcll(mk);
            }
        } else {
            // slow path (rare): R2-proven coarse top-16 + fp64 rescore
            int cand[NCAND];
            #pragma unroll
            for (int r = 0; r < NCAND; r++) {
                float bv = sv[0]; int bj = 0;
                #pragma unroll
                for (int j = 1; j < 8; j++) if (sv[j] > bv) { bv = sv[j]; bj = j; }
                int bidx = lane + 64 * bj;
                #pragma unroll
                for (int off = 32; off > 0; off >>= 1) {
                    float ov = __shfl_xor(bv, off);
                    int   oi = __shfl_xor(bidx, off);
                    if (ov > bv || (ov == bv && oi < bidx)) { bv = ov; bidx = oi; }
                }
                cand[r] = bidx;
                int jj = bidx >> 6;
                if ((bidx & 63) == lane) {
                    #pragma unroll
                    for (int j = 0; j < 8; j++) if (j == jj) sv[j] = -INFINITY;
                }
            }
            double qd[8];
            #pragma unroll
            for (int j = 0; j < 8; j++)
                qd[j] = (double)query[(size_t)tok * DDIM + qoff + lane + 64 * j];
            double rv[NCAND];
            #pragma unroll
            for (int r = 0; r < NCAND; r++) {
                const float* __restrict__ crow = &cbf[(size_t)cand[r] * KDIM];
                double a = 0.0;
                #pragma unroll
                for (int j = 0; j < 8; j++)
                    a = fma(qd[j], (double)crow[lane + 64 * j], a);
                #pragma unroll
                for (int off = 32; off > 0; off >>= 1)
                    a += __shfl_xor(a, off);
                rv[r] = a;
            }
            if (lane == 0) {
                #pragma unroll
                for (int r = 0; r < NCAND; r++) {
                    int rk = 0;
                    #pragma unroll
                    for (int mm = 0; mm < NCAND; mm++)
                        if (rv[mm] > rv[r] || (rv[mm] == rv[r] && cand[mm] < cand[r])) rk++;
                    if (rk < TOPK) {
                        tk_idx[((size_t)tok * 2 + half) * TOPK + rk] = cand[r];
                        tk_val[((size_t)tok * 2 + half) * TOPK + rk] = (float)rv[r];
                    }
                }
            }
        }
    }
}

// ---------------------------------------------------------------------------
// Kernel 2: one wave per token. softmax(8)x2 -> 64 weighted value rows.
// ---------------------------------------------------------------------------
__global__ __launch_bounds__(256)
void gather_kernel(const float* __restrict__ values,
                   const int*   __restrict__ tk_idx,
                   const float* __restrict__ tk_val,
                   float* __restrict__ out)
{
    const int tid  = threadIdx.x;
    const int lane = tid & 63;
    const int tok  = blockIdx.x * 4 + (tid >> 6);

    const int b1 = (tok * 2 + 0) * TOPK;
    const int b2 = (tok * 2 + 1) * TOPK;

    float v1[8], v2[8]; int i1[8], i2[8];
    #pragma unroll
    for (int j = 0; j < 8; j++) {
        i1[j] = tk_idx[b1 + j]; v1[j] = tk_val[b1 + j];
        i2[j] = tk_idx[b2 + j]; v2[j] = tk_val[b2 + j];
    }

    float m1 = v1[0], m2 = v2[0];
    #pragma unroll
    for (int j = 1; j < 8; j++) { m1 = fmaxf(m1, v1[j]); m2 = fmaxf(m2, v2[j]); }

    float w1[8], w2[8], s1 = 0.f, s2 = 0.f;
    #pragma unroll
    for (int j = 0; j < 8; j++) {
        w1[j] = expf(v1[j] - m1); s1 += w1[j];
        w2[j] = expf(v2[j] - m2); s2 += w2[j];
    }
    const float inv1 = 1.f / s1, inv2 = 1.f / s2;
    #pragma unroll
    for (int j = 0; j < 8; j++) { w1[j] *= inv1; w2[j] *= inv2; }

    float2 acc = make_float2(0.f, 0.f);
    #pragma unroll
    for (int i = 0; i < 8; i++) {
        const int rb = i1[i] * SUB;
        const float wi = w1[i];
        #pragma unroll
        for (int j = 0; j < 8; j++) {
            const float w = wi * w2[j];
            const float* __restrict__ row = values + (size_t)(rb + i2[j]) * VDIM;
            float2 tv = *(const float2*)&row[lane * 2];
            acc.x = fmaf(w, tv.x, acc.x);
            acc.y = fmaf(w, tv.y, acc.y);
        }
    }
    *(float2*)&out[(size_t)tok * VDIM + lane * 2] = acc;
}

extern "C" void kernel_launch(void* const* d_in, const int* in_sizes, int n_in,
                              void* d_out, int out_size, void* d_ws, size_t ws_size,
                              hipStream_t stream) {
    const float* query  = (const float*)d_in[0];
    const float* cb1    = (const float*)d_in[1];
    const float* cb2    = (const float*)d_in[2];
    const float* values = (const float*)d_in[3];
    float* out = (float*)d_out;

    char* ws = (char*)d_ws;
    int*            tk_idx = (int*)ws;                                  // 1 MB
    float*          tk_val = (float*)(ws + (1u << 20));                 // 1 MB
    unsigned short* cbh1   = (unsigned short*)(ws + (2u << 20));                     // 512 KB
    unsigned short* cbl1   = (unsigned short*)(ws + (2u << 20) + 1 * (512u << 10));
    unsigned short* cbh2   = (unsigned short*)(ws + (2u << 20) + 2 * (512u << 10));
    unsigned short* cbl2   = (unsigned short*)(ws + (2u << 20) + 3 * (512u << 10));

    cvt_kernel<<<SUB * KDIM * 2 / (256 * 8), 256, 0, stream>>>(cb1, cb2, cbh1, cbl1, cbh2, cbl2);
    dim3 g1(NTOK / TMB, 2);
    score_topk_mfma<<<g1, 512, 0, stream>>>(query, cb1, cb2, cbh1, cbl1, cbh2, cbl2, tk_idx, tk_val);
    gather_kernel<<<NTOK / 4, 256, 0, stream>>>(values, tk_idx, tk_val, out);
}

// Round 4
// 228.532 us; speedup vs baseline: 2.8155x; 1.6795x over previous
//
#include <hip/hip_runtime.h>
#include <hip/hip_bf16.h>
#include <math.h>

#define NTOK 16384
#define DDIM 1024
#define HALF 512
#define SUB  512
#define KDIM 512
#define TOPK 8
#define NCAND 16
#define VDIM 128
#define TMB 32

typedef __attribute__((ext_vector_type(8))) short bf16x8;
typedef __attribute__((ext_vector_type(4))) float f32x4;

static __device__ __forceinline__ unsigned short f2bf(float x) {
    union { float f; unsigned u; } v; v.f = x;
    unsigned r = v.u + 0x7FFF + ((v.u >> 16) & 1);   // RNE
    return (unsigned short)(r >> 16);
}

static __device__ __forceinline__ void split_bf(float x, unsigned short& h, unsigned short& l) {
    h = f2bf(x);
    union { unsigned u; float f; } hv; hv.u = ((unsigned)h) << 16;
    l = f2bf(x - hv.f);
}

// ---------------------------------------------------------------------------
// Kernel 0: codebooks -> bf16 hi/lo in MFMA-B-fragment order:
//   Bfrag[half][candhalf][nt][kc][lane][8], lane = lh*16 + l15,
//   elem (n = candhalf*256 + nt*16 + l15, k = kc*32 + lh*8 + j)
// One int4 (8 bf16) per thread per array. 65536 int4 each.
// ---------------------------------------------------------------------------
__global__ __launch_bounds__(256)
void cvt_bfrag(const float* __restrict__ cb1, const float* __restrict__ cb2,
               unsigned short* __restrict__ Bh, unsigned short* __restrict__ Bl)
{
    int fid  = blockIdx.x * 256 + threadIdx.x;   // 0..65535
    int lane = fid & 63;
    int kc   = (fid >> 6) & 15;
    int nt   = (fid >> 10) & 15;
    int chh  = (fid >> 14) & 3;                  // half*2 + candhalf
    const float* cb = (chh >> 1) ? cb2 : cb1;
    int n  = (chh & 1) * 256 + nt * 16 + (lane & 15);
    int kb = kc * 32 + (lane >> 4) * 8;
    const float* src = cb + (size_t)n * KDIM + kb;
    float4 f0 = *(const float4*)src;
    float4 f1 = *(const float4*)(src + 4);
    unsigned short hh[8], ll[8];
    split_bf(f0.x, hh[0], ll[0]); split_bf(f0.y, hh[1], ll[1]);
    split_bf(f0.z, hh[2], ll[2]); split_bf(f0.w, hh[3], ll[3]);
    split_bf(f1.x, hh[4], ll[4]); split_bf(f1.y, hh[5], ll[5]);
    split_bf(f1.z, hh[6], ll[6]); split_bf(f1.w, hh[7], ll[7]);
    *(int4*)(Bh + (size_t)fid * 8) = *(const int4*)hh;
    *(int4*)(Bl + (size_t)fid * 8) = *(const int4*)ll;
}

// ---------------------------------------------------------------------------
// Kernel 1: 256 threads (4 waves), 32 tokens, one half.
//   wave w: tokgrp = w>>1 (16 tokens), candhalf = w&1 (256 cands).
//   A: fp32->bf16 hi/lo staged once to swizzled LDS, then held in registers.
//   B: streamed global->register (fragment-ordered), 8-deep prefetch ring.
//   3 barriers total. Phase 2: gated ballot-bisect top-8 + rare fp64 path.
// ---------------------------------------------------------------------------
__global__ __launch_bounds__(256, 2)
void score_topk_mfma(const float* __restrict__ query,
                     const float* __restrict__ cb1f,
                     const float* __restrict__ cb2f,
                     const unsigned short* __restrict__ Bh,
                     const unsigned short* __restrict__ Bl,
                     int*   __restrict__ tk_idx,
                     float* __restrict__ tk_val)
{
    __shared__ char smem[65536];
    char* sAh = smem;            // bf16 [32][512] swizzled (16B chunks XOR row&7)
    char* sAl = smem + 32768;
    float* sS = (float*)smem;    // phase 2: fp32 [32][512] overlays A

    const int tid  = threadIdx.x;
    const int hf   = blockIdx.y;
    const int tok0 = blockIdx.x * TMB;
    const float* __restrict__ cbf = hf ? cb2f : cb1f;
    const int qoff = hf * HALF;

    const int lane = tid & 63;
    const int wid  = tid >> 6;          // 0..3
    const int tokg = wid >> 1;          // 0,1
    const int chf  = wid & 1;           // cand half
    const int l15  = lane & 15;
    const int lh   = lane >> 4;
    const int l7   = lane & 7;

    // ---- stage A: 32 tok x 512 k fp32 -> bf16 hi/lo, swizzled LDS ----
    #pragma unroll
    for (int i = 0; i < 8; i++) {
        int c   = i * 256 + tid;        // 0..2047 16B-chunks
        int row = c >> 6;
        int b8  = c & 63;
        const float* src = query + (size_t)(tok0 + row) * DDIM + qoff + b8 * 8;
        float4 f0 = *(const float4*)(src);
        float4 f1 = *(const float4*)(src + 4);
        unsigned short hh[8], ll[8];
        split_bf(f0.x, hh[0], ll[0]); split_bf(f0.y, hh[1], ll[1]);
        split_bf(f0.z, hh[2], ll[2]); split_bf(f0.w, hh[3], ll[3]);
        split_bf(f1.x, hh[4], ll[4]); split_bf(f1.y, hh[5], ll[5]);
        split_bf(f1.z, hh[6], ll[6]); split_bf(f1.w, hh[7], ll[7]);
        int boff = row * 1024 + ((b8 * 16) ^ ((row & 7) << 4));
        *(int4*)(sAh + boff) = *(const int4*)hh;
        *(int4*)(sAl + boff) = *(const int4*)ll;
    }
    __syncthreads();

    // ---- A panel -> registers (conflict-free swizzled ds_read_b128) ----
    bf16x8 ah[16], al[16];
    #pragma unroll
    for (int kc = 0; kc < 16; kc++) {
        int aoff = (tokg * 16 + l15) * 1024 + ((kc * 64 + lh * 16) ^ (l7 << 4));
        ah[kc] = *(const bf16x8*)(sAh + aoff);
        al[kc] = *(const bf16x8*)(sAl + aoff);
    }
    __syncthreads();   // A regs captured; sS may now overwrite sA

    // ---- B stream: 256 steps (16 nt x 16 kc), 8-deep register ring ----
    const char* bhp = (const char*)Bh + (size_t)(hf * 2 + chf) * 262144 + lane * 16;
    const char* blp = (const char*)Bl + (size_t)(hf * 2 + chf) * 262144 + lane * 16;
    int4 rh[8], rl[8];
    #pragma unroll
    for (int p = 0; p < 8; p++) {
        rh[p] = *(const int4*)(bhp + p * 1024);
        rl[p] = *(const int4*)(blp + p * 1024);
    }

    for (int nt = 0; nt < 16; nt++) {
        f32x4 aX = {0.f,0.f,0.f,0.f}, aY = {0.f,0.f,0.f,0.f}, aZ = {0.f,0.f,0.f,0.f};
        #pragma unroll
        for (int kc = 0; kc < 16; kc++) {
            const int s = nt * 16 + kc;
            const int slot = kc & 7;
            union { int4 i; bf16x8 b; } ubh, ubl;
            ubh.i = rh[slot]; ubl.i = rl[slot];
            rh[slot] = *(const int4*)(bhp + ((s + 8) & 255) * 1024);
            rl[slot] = *(const int4*)(blp + ((s + 8) & 255) * 1024);
            aX = __builtin_amdgcn_mfma_f32_16x16x32_bf16(ah[kc], ubh.b, aX, 0, 0, 0);
            aY = __builtin_amdgcn_mfma_f32_16x16x32_bf16(al[kc], ubh.b, aY, 0, 0, 0);
            aZ = __builtin_amdgcn_mfma_f32_16x16x32_bf16(ah[kc], ubl.b, aZ, 0, 0, 0);
        }
        f32x4 sc = aX + aY + aZ;
        // C/D layout: col = lane&15 (cand), row = (lane>>4)*4 + r (token)
        #pragma unroll
        for (int r = 0; r < 4; r++) {
            int t = tokg * 16 + lh * 4 + r;
            int c = chf * 256 + nt * 16 + l15;
            sS[t * SUB + (c ^ (lh << 3))] = sc[r];   // hash = ((t>>2)&3)<<3 = lh<<3
        }
    }
    __syncthreads();

    // ---- phase 2: per wave, 8 tokens ----
    for (int v = 0; v < 8; v++) {
        const int t   = wid * 8 + v;
        const int tok = tok0 + t;
        const int hsh = ((t >> 2) & 3) << 3;

        float sv[8];
        #pragma unroll
        for (int j = 0; j < 8; j++) sv[j] = sS[t * SUB + ((lane + 64 * j) ^ hsh)];

        float m = sv[0];
        #pragma unroll
        for (int j = 1; j < 8; j++) m = fmaxf(m, sv[j]);
        #pragma unroll
        for (int off = 32; off > 0; off >>= 1) m = fmaxf(m, __shfl_xor(m, off));

        auto wave_cnt = [&](float tau) -> int {
            int c = 0;
            #pragma unroll
            for (int j = 0; j < 8; j++)
                c += __popcll(__ballot(sv[j] > tau));
            return c;
        };

        float lo = m - 3.0f, hi = m;
        while (wave_cnt(lo) < 9) lo -= 3.0f;
        for (int it = 0; it < 17; it++) {
            float mid = 0.5f * (lo + hi);
            if (wave_cnt(mid) >= 9) lo = mid; else hi = mid;
        }
        int ch8 = wave_cnt(hi);

        float v8 = 1e30f, v9 = -1e30f;
        #pragma unroll
        for (int j = 0; j < 8; j++) {
            bool sel = sv[j] > hi;
            v8 = sel ? fminf(v8, sv[j]) : v8;
            v9 = sel ? v9 : fmaxf(v9, sv[j]);
        }
        #pragma unroll
        for (int off = 32; off > 0; off >>= 1) {
            v8 = fminf(v8, __shfl_xor(v8, off));
            v9 = fmaxf(v9, __shfl_xor(v9, off));
        }

        if (ch8 == 8 && (v8 - v9) > 6e-5f) {
            int base = 0;
            #pragma unroll
            for (int j = 0; j < 8; j++) {
                unsigned long long mk = __ballot(sv[j] > hi);
                if (sv[j] > hi) {
                    int pos = base + __popcll(mk & ((1ULL << lane) - 1ULL));
                    tk_idx[((size_t)tok * 2 + hf) * TOPK + pos] = lane + 64 * j;
                    tk_val[((size_t)tok * 2 + hf) * TOPK + pos] = sv[j];
                }
                base += __popcll(mk);
            }
        } else {
            // slow path (rare): coarse top-16 + fp64 rescore, exact ordering
            int cand[NCAND];
            #pragma unroll
            for (int r = 0; r < NCAND; r++) {
                float bv = sv[0]; int bj = 0;
                #pragma unroll
                for (int j = 1; j < 8; j++) if (sv[j] > bv) { bv = sv[j]; bj = j; }
                int bidx = lane + 64 * bj;
                #pragma unroll
                for (int off = 32; off > 0; off >>= 1) {
                    float ov = __shfl_xor(bv, off);
                    int   oi = __shfl_xor(bidx, off);
                    if (ov > bv || (ov == bv && oi < bidx)) { bv = ov; bidx = oi; }
                }
                cand[r] = bidx;
                int jj = bidx >> 6;
                if ((bidx & 63) == lane) {
                    #pragma unroll
                    for (int j = 0; j < 8; j++) if (j == jj) sv[j] = -INFINITY;
                }
            }
            double qd[8];
            #pragma unroll
            for (int j = 0; j < 8; j++)
                qd[j] = (double)query[(size_t)tok * DDIM + qoff + lane + 64 * j];
            double rv[NCAND];
            #pragma unroll
            for (int r = 0; r < NCAND; r++) {
                const float* __restrict__ crow = &cbf[(size_t)cand[r] * KDIM];
                double a = 0.0;
                #pragma unroll
                for (int j = 0; j < 8; j++)
                    a = fma(qd[j], (double)crow[lane + 64 * j], a);
                #pragma unroll
                for (int off = 32; off > 0; off >>= 1)
                    a += __shfl_xor(a, off);
                rv[r] = a;
            }
            if (lane == 0) {
                #pragma unroll
                for (int r = 0; r < NCAND; r++) {
                    int rk = 0;
                    #pragma unroll
                    for (int mm = 0; mm < NCAND; mm++)
                        if (rv[mm] > rv[r] || (rv[mm] == rv[r] && cand[mm] < cand[r])) rk++;
                    if (rk < TOPK) {
                        tk_idx[((size_t)tok * 2 + hf) * TOPK + rk] = cand[r];
                        tk_val[((size_t)tok * 2 + hf) * TOPK + rk] = (float)rv[r];
                    }
                }
            }
        }
    }
}

// ---------------------------------------------------------------------------
// Kernel 2: one wave per token. softmax(8)x2 -> 64 weighted value rows.
// ---------------------------------------------------------------------------
__global__ __launch_bounds__(256)
void gather_kernel(const float* __restrict__ values,
                   const int*   __restrict__ tk_idx,
                   const float* __restrict__ tk_val,
                   float* __restrict__ out)
{
    const int tid  = threadIdx.x;
    const int lane = tid & 63;
    const int tok  = blockIdx.x * 4 + (tid >> 6);

    const int b1 = (tok * 2 + 0) * TOPK;
    const int b2 = (tok * 2 + 1) * TOPK;

    float v1[8], v2[8]; int i1[8], i2[8];
    #pragma unroll
    for (int j = 0; j < 8; j++) {
        i1[j] = tk_idx[b1 + j]; v1[j] = tk_val[b1 + j];
        i2[j] = tk_idx[b2 + j]; v2[j] = tk_val[b2 + j];
    }

    float m1 = v1[0], m2 = v2[0];
    #pragma unroll
    for (int j = 1; j < 8; j++) { m1 = fmaxf(m1, v1[j]); m2 = fmaxf(m2, v2[j]); }

    float w1[8], w2[8], s1 = 0.f, s2 = 0.f;
    #pragma unroll
    for (int j = 0; j < 8; j++) {
        w1[j] = expf(v1[j] - m1); s1 += w1[j];
        w2[j] = expf(v2[j] - m2); s2 += w2[j];
    }
    const float inv1 = 1.f / s1, inv2 = 1.f / s2;
    #pragma unroll
    for (int j = 0; j < 8; j++) { w1[j] *= inv1; w2[j] *= inv2; }

    float2 acc = make_float2(0.f, 0.f);
    #pragma unroll
    for (int i = 0; i < 8; i++) {
        const int rb = i1[i] * SUB;
        const float wi = w1[i];
        #pragma unroll
        for (int j = 0; j < 8; j++) {
            const float w = wi * w2[j];
            const float* __restrict__ row = values + (size_t)(rb + i2[j]) * VDIM;
            float2 tv = *(const float2*)&row[lane * 2];
            acc.x = fmaf(w, tv.x, acc.x);
            acc.y = fmaf(w, tv.y, acc.y);
        }
    }
    *(float2*)&out[(size_t)tok * VDIM + lane * 2] = acc;
}

extern "C" void kernel_launch(void* const* d_in, const int* in_sizes, int n_in,
                              void* d_out, int out_size, void* d_ws, size_t ws_size,
                              hipStream_t stream) {
    const float* query  = (const float*)d_in[0];
    const float* cb1    = (const float*)d_in[1];
    const float* cb2    = (const float*)d_in[2];
    const float* values = (const float*)d_in[3];
    float* out = (float*)d_out;

    char* ws = (char*)d_ws;
    int*            tk_idx = (int*)ws;                           // 1 MB
    float*          tk_val = (float*)(ws + (1u << 20));          // 1 MB
    unsigned short* Bh     = (unsigned short*)(ws + (2u << 20)); // 1 MB
    unsigned short* Bl     = (unsigned short*)(ws + (3u << 20)); // 1 MB

    cvt_bfrag<<<256, 256, 0, stream>>>(cb1, cb2, Bh, Bl);
    dim3 g1(NTOK / TMB, 2);
    score_topk_mfma<<<g1, 256, 0, stream>>>(query, cb1, cb2, Bh, Bl, tk_idx, tk_val);
    gather_kernel<<<NTOK / 4, 256, 0, stream>>>(values, tk_idx, tk_val, out);
}

// Round 5
// 215.470 us; speedup vs baseline: 2.9861x; 1.0606x over previous
//
#include <hip/hip_runtime.h>
#include <hip/hip_bf16.h>
#include <math.h>

#define NTOK 16384
#define DDIM 1024
#define HALF 512
#define SUB  512
#define KDIM 512
#define TOPK 8
#define NCAND 16
#define VDIM 128
#define TMB 16          // tokens per block (score kernel)

typedef __attribute__((ext_vector_type(8))) short bf16x8;
typedef __attribute__((ext_vector_type(4))) float f32x4;

static __device__ __forceinline__ unsigned short f2bf(float x) {
    union { float f; unsigned u; } v; v.f = x;
    unsigned r = v.u + 0x7FFF + ((v.u >> 16) & 1);   // RNE
    return (unsigned short)(r >> 16);
}

static __device__ __forceinline__ void split_bf(float x, unsigned short& h, unsigned short& l) {
    h = f2bf(x);
    union { unsigned u; float f; } hv; hv.u = ((unsigned)h) << 16;
    l = f2bf(x - hv.f);
}

// ---------------------------------------------------------------------------
// Kernel 0: codebooks -> bf16 hi/lo in MFMA-B-fragment order:
//   Bfrag[half][cq(4)][kc(16)][nt(8)][lane(64)][8 bf16]
//   elem: n = cq*128 + nt*16 + (lane&15), k = kc*32 + (lane>>4)*8 + j
// ---------------------------------------------------------------------------
__global__ __launch_bounds__(256)
void cvt_bfrag(const float* __restrict__ cb1, const float* __restrict__ cb2,
               unsigned short* __restrict__ Bh, unsigned short* __restrict__ Bl)
{
    int fid  = blockIdx.x * 256 + threadIdx.x;   // 0..65535
    int lane = fid & 63;
    int nt   = (fid >> 6) & 7;
    int kc   = (fid >> 9) & 15;
    int cq   = (fid >> 13) & 3;
    int hf   = (fid >> 15) & 1;
    const float* cb = hf ? cb2 : cb1;
    int n  = cq * 128 + nt * 16 + (lane & 15);
    int kb = kc * 32 + (lane >> 4) * 8;
    const float* src = cb + (size_t)n * KDIM + kb;
    float4 f0 = *(const float4*)src;
    float4 f1 = *(const float4*)(src + 4);
    unsigned short hh[8], ll[8];
    split_bf(f0.x, hh[0], ll[0]); split_bf(f0.y, hh[1], ll[1]);
    split_bf(f0.z, hh[2], ll[2]); split_bf(f0.w, hh[3], ll[3]);
    split_bf(f1.x, hh[4], ll[4]); split_bf(f1.y, hh[5], ll[5]);
    split_bf(f1.z, hh[6], ll[6]); split_bf(f1.w, hh[7], ll[7]);
    *(int4*)(Bh + (size_t)fid * 8) = *(const int4*)hh;
    *(int4*)(Bl + (size_t)fid * 8) = *(const int4*)ll;
}

// ---------------------------------------------------------------------------
// Kernel 1: 256 threads (4 waves), 16 tokens, one half. Wave = cand quarter.
//   A: fp32->bf16 hi/lo staged to 32 KB swizzled LDS, re-read per kc (2 reads).
//   B: streamed global->register, 4-deep prefetch ring, kc-outer/nt-inner.
//   acc[nt] accumulates the 3 split-bf16 MFMA terms. 3 barriers total.
//   Phase 2: gated ballot-bisect top-8 + rare fp64 slow path (proven R2-R4).
// ---------------------------------------------------------------------------
__global__ __launch_bounds__(256, 4)
void score_topk_mfma(const float* __restrict__ query,
                     const float* __restrict__ cb1f,
                     const float* __restrict__ cb2f,
                     const unsigned short* __restrict__ Bh,
                     const unsigned short* __restrict__ Bl,
                     int*   __restrict__ tk_idx,
                     float* __restrict__ tk_val)
{
    __shared__ char smem[32768];
    char* sAh = smem;            // bf16 [16][512] swizzled (16B chunks XOR row&7)
    char* sAl = smem + 16384;
    float* sS = (float*)smem;    // phase 2: fp32 [16][512] overlays A

    const int tid  = threadIdx.x;
    const int hf   = blockIdx.y;
    const int tok0 = blockIdx.x * TMB;
    const float* __restrict__ cbf = hf ? cb2f : cb1f;
    const int qoff = hf * HALF;

    const int lane = tid & 63;
    const int wid  = tid >> 6;          // 0..3 = cand quarter
    const int l15  = lane & 15;
    const int lh   = lane >> 4;
    const int l7   = lane & 7;

    // ---- stage A: 16 tok x 512 k fp32 -> bf16 hi/lo, swizzled LDS ----
    #pragma unroll
    for (int i = 0; i < 4; i++) {
        int c   = i * 256 + tid;        // 0..1023 16B-chunks
        int row = c >> 6;
        int b8  = c & 63;
        const float* src = query + (size_t)(tok0 + row) * DDIM + qoff + b8 * 8;
        float4 f0 = *(const float4*)(src);
        float4 f1 = *(const float4*)(src + 4);
        unsigned short hh[8], ll[8];
        split_bf(f0.x, hh[0], ll[0]); split_bf(f0.y, hh[1], ll[1]);
        split_bf(f0.z, hh[2], ll[2]); split_bf(f0.w, hh[3], ll[3]);
        split_bf(f1.x, hh[4], ll[4]); split_bf(f1.y, hh[5], ll[5]);
        split_bf(f1.z, hh[6], ll[6]); split_bf(f1.w, hh[7], ll[7]);
        int boff = row * 1024 + ((b8 * 16) ^ ((row & 7) << 4));
        *(int4*)(sAh + boff) = *(const int4*)hh;
        *(int4*)(sAl + boff) = *(const int4*)ll;
    }
    __syncthreads();

    // ---- B stream pointers (fragment-ordered, step s = kc*8 + nt) ----
    const char* bhp = (const char*)Bh + (size_t)(hf * 4 + wid) * 131072 + lane * 16;
    const char* blp = (const char*)Bl + (size_t)(hf * 4 + wid) * 131072 + lane * 16;

    int4 rh[4], rl[4];
    #pragma unroll
    for (int p = 0; p < 4; p++) {
        rh[p] = *(const int4*)(bhp + p * 1024);
        rl[p] = *(const int4*)(blp + p * 1024);
    }

    f32x4 acc[8];
    #pragma unroll
    for (int nt = 0; nt < 8; nt++) acc[nt] = (f32x4){0.f, 0.f, 0.f, 0.f};

    for (int kc = 0; kc < 16; kc++) {
        const int aoff = l15 * 1024 + ((kc * 64 + lh * 16) ^ (l7 << 4));
        const bf16x8 ah = *(const bf16x8*)(sAh + aoff);
        const bf16x8 al = *(const bf16x8*)(sAl + aoff);
        #pragma unroll
        for (int nt = 0; nt < 8; nt++) {
            const int slot = nt & 3;
            union { int4 i; bf16x8 b; } ubh, ubl;
            ubh.i = rh[slot]; ubl.i = rl[slot];
            const int sp = (kc * 8 + nt + 4) & 127;
            rh[slot] = *(const int4*)(bhp + sp * 1024);
            rl[slot] = *(const int4*)(blp + sp * 1024);
            acc[nt] = __builtin_amdgcn_mfma_f32_16x16x32_bf16(ah, ubh.b, acc[nt], 0, 0, 0);
            acc[nt] = __builtin_amdgcn_mfma_f32_16x16x32_bf16(al, ubh.b, acc[nt], 0, 0, 0);
            acc[nt] = __builtin_amdgcn_mfma_f32_16x16x32_bf16(ah, ubl.b, acc[nt], 0, 0, 0);
        }
    }
    __syncthreads();   // all A reads done; sS may overwrite sA

    // ---- dump scores: C/D layout row=(lane>>4)*4+r (token), col=lane&15 ----
    #pragma unroll
    for (int nt = 0; nt < 8; nt++)
        #pragma unroll
        for (int r = 0; r < 4; r++) {
            int t = lh * 4 + r;
            int c = wid * 128 + nt * 16 + l15;
            sS[t * SUB + (c ^ (lh << 3))] = acc[nt][r];   // hash = ((t>>2)&3)<<3
        }
    __syncthreads();

    // ---- phase 2: per wave, 4 tokens ----
    for (int v = 0; v < 4; v++) {
        const int t   = wid * 4 + v;
        const int tok = tok0 + t;
        const int hsh = ((t >> 2) & 3) << 3;

        float sv[8];
        #pragma unroll
        for (int j = 0; j < 8; j++) sv[j] = sS[t * SUB + ((lane + 64 * j) ^ hsh)];

        float m = sv[0];
        #pragma unroll
        for (int j = 1; j < 8; j++) m = fmaxf(m, sv[j]);
        #pragma unroll
        for (int off = 32; off > 0; off >>= 1) m = fmaxf(m, __shfl_xor(m, off));

        auto wave_cnt = [&](float tau) -> int {
            int c = 0;
            #pragma unroll
            for (int j = 0; j < 8; j++)
                c += __popcll(__ballot(sv[j] > tau));
            return c;
        };

        float lo = m - 0.5f, hi = m;
        while (wave_cnt(lo) < 9) lo -= 0.5f;
        for (int it = 0; it < 14; it++) {
            float mid = 0.5f * (lo + hi);
            if (wave_cnt(mid) >= 9) lo = mid; else hi = mid;
        }
        int ch8 = wave_cnt(hi);

        float v8 = 1e30f, v9 = -1e30f;
        #pragma unroll
        for (int j = 0; j < 8; j++) {
            bool sel = sv[j] > hi;
            v8 = sel ? fminf(v8, sv[j]) : v8;
            v9 = sel ? v9 : fmaxf(v9, sv[j]);
        }
        #pragma unroll
        for (int off = 32; off > 0; off >>= 1) {
            v8 = fminf(v8, __shfl_xor(v8, off));
            v9 = fmaxf(v9, __shfl_xor(v9, off));
        }

        if (ch8 == 8 && (v8 - v9) > 6e-5f) {
            int base = 0;
            #pragma unroll
            for (int j = 0; j < 8; j++) {
                unsigned long long mk = __ballot(sv[j] > hi);
                if (sv[j] > hi) {
                    int pos = base + __popcll(mk & ((1ULL << lane) - 1ULL));
                    tk_idx[((size_t)tok * 2 + hf) * TOPK + pos] = lane + 64 * j;
                    tk_val[((size_t)tok * 2 + hf) * TOPK + pos] = sv[j];
                }
                base += __popcll(mk);
            }
        } else {
            // slow path (rare): coarse top-16 + fp64 rescore, exact ordering
            int cand[NCAND];
            #pragma unroll
            for (int r = 0; r < NCAND; r++) {
                float bv = sv[0]; int bj = 0;
                #pragma unroll
                for (int j = 1; j < 8; j++) if (sv[j] > bv) { bv = sv[j]; bj = j; }
                int bidx = lane + 64 * bj;
                #pragma unroll
                for (int off = 32; off > 0; off >>= 1) {
                    float ov = __shfl_xor(bv, off);
                    int   oi = __shfl_xor(bidx, off);
                    if (ov > bv || (ov == bv && oi < bidx)) { bv = ov; bidx = oi; }
                }
                cand[r] = bidx;
                int jj = bidx >> 6;
                if ((bidx & 63) == lane) {
                    #pragma unroll
                    for (int j = 0; j < 8; j++) if (j == jj) sv[j] = -INFINITY;
                }
            }
            double qd[8];
            #pragma unroll
            for (int j = 0; j < 8; j++)
                qd[j] = (double)query[(size_t)tok * DDIM + qoff + lane + 64 * j];
            double rv[NCAND];
            #pragma unroll
            for (int r = 0; r < NCAND; r++) {
                const float* __restrict__ crow = &cbf[(size_t)cand[r] * KDIM];
                double a = 0.0;
                #pragma unroll
                for (int j = 0; j < 8; j++)
                    a = fma(qd[j], (double)crow[lane + 64 * j], a);
                #pragma unroll
                for (int off = 32; off > 0; off >>= 1)
                    a += __shfl_xor(a, off);
                rv[r] = a;
            }
            if (lane == 0) {
                #pragma unroll
                for (int r = 0; r < NCAND; r++) {
                    int rk = 0;
                    #pragma unroll
                    for (int mm = 0; mm < NCAND; mm++)
                        if (rv[mm] > rv[r] || (rv[mm] == rv[r] && cand[mm] < cand[r])) rk++;
                    if (rk < TOPK) {
                        tk_idx[((size_t)tok * 2 + hf) * TOPK + rk] = cand[r];
                        tk_val[((size_t)tok * 2 + hf) * TOPK + rk] = (float)rv[r];
                    }
                }
            }
        }
    }
}

// ---------------------------------------------------------------------------
// Kernel 2: one wave per token. softmax(8)x2 -> 64 weighted value rows.
// ---------------------------------------------------------------------------
__global__ __launch_bounds__(256)
void gather_kernel(const float* __restrict__ values,
                   const int*   __restrict__ tk_idx,
                   const float* __restrict__ tk_val,
                   float* __restrict__ out)
{
    const int tid  = threadIdx.x;
    const int lane = tid & 63;
    const int tok  = blockIdx.x * 4 + (tid >> 6);

    const int b1 = (tok * 2 + 0) * TOPK;
    const int b2 = (tok * 2 + 1) * TOPK;

    float v1[8], v2[8]; int i1[8], i2[8];
    #pragma unroll
    for (int j = 0; j < 8; j++) {
        i1[j] = tk_idx[b1 + j]; v1[j] = tk_val[b1 + j];
        i2[j] = tk_idx[b2 + j]; v2[j] = tk_val[b2 + j];
    }

    float m1 = v1[0], m2 = v2[0];
    #pragma unroll
    for (int j = 1; j < 8; j++) { m1 = fmaxf(m1, v1[j]); m2 = fmaxf(m2, v2[j]); }

    float w1[8], w2[8], s1 = 0.f, s2 = 0.f;
    #pragma unroll
    for (int j = 0; j < 8; j++) {
        w1[j] = expf(v1[j] - m1); s1 += w1[j];
        w2[j] = expf(v2[j] - m2); s2 += w2[j];
    }
    const float inv1 = 1.f / s1, inv2 = 1.f / s2;
    #pragma unroll
    for (int j = 0; j < 8; j++) { w1[j] *= inv1; w2[j] *= inv2; }

    float2 acc = make_float2(0.f, 0.f);
    #pragma unroll
    for (int i = 0; i < 8; i++) {
        const int rb = i1[i] * SUB;
        const float wi = w1[i];
        #pragma unroll
        for (int j = 0; j < 8; j++) {
            const float w = wi * w2[j];
            const float* __restrict__ row = values + (size_t)(rb + i2[j]) * VDIM;
            float2 tv = *(const float2*)&row[lane * 2];
            acc.x = fmaf(w, tv.x, acc.x);
            acc.y = fmaf(w, tv.y, acc.y);
        }
    }
    *(float2*)&out[(size_t)tok * VDIM + lane * 2] = acc;
}

extern "C" void kernel_launch(void* const* d_in, const int* in_sizes, int n_in,
                              void* d_out, int out_size, void* d_ws, size_t ws_size,
                              hipStream_t stream) {
    const float* query  = (const float*)d_in[0];
    const float* cb1    = (const float*)d_in[1];
    const float* cb2    = (const float*)d_in[2];
    const float* values = (const float*)d_in[3];
    float* out = (float*)d_out;

    char* ws = (char*)d_ws;
    int*            tk_idx = (int*)ws;                           // 1 MB
    float*          tk_val = (float*)(ws + (1u << 20));          // 1 MB
    unsigned short* Bh     = (unsigned short*)(ws + (2u << 20)); // 1 MB
    unsigned short* Bl     = (unsigned short*)(ws + (3u << 20)); // 1 MB

    cvt_bfrag<<<256, 256, 0, stream>>>(cb1, cb2, Bh, Bl);
    dim3 g1(NTOK / TMB, 2);
    score_topk_mfma<<<g1, 256, 0, stream>>>(query, cb1, cb2, Bh, Bl, tk_idx, tk_val);
    gather_kernel<<<NTOK / 4, 256, 0, stream>>>(values, tk_idx, tk_val, out);
}

// Round 6
// 207.348 us; speedup vs baseline: 3.1031x; 1.0392x over previous
//
#include <hip/hip_runtime.h>
#include <hip/hip_bf16.h>
#include <math.h>

#define NTOK 16384
#define DDIM 1024
#define HALF 512
#define SUB  512
#define KDIM 512
#define TOPK 8
#define NCAND 16
#define VDIM 128
#define TMB 32          // tokens per block (score kernel)

typedef __attribute__((ext_vector_type(8))) short bf16x8;
typedef __attribute__((ext_vector_type(4))) float f32x4;

static __device__ __forceinline__ unsigned short f2bf(float x) {
    union { float f; unsigned u; } v; v.f = x;
    unsigned r = v.u + 0x7FFF + ((v.u >> 16) & 1);   // RNE
    return (unsigned short)(r >> 16);
}

static __device__ __forceinline__ void split_bf(float x, unsigned short& h, unsigned short& l) {
    h = f2bf(x);
    union { unsigned u; float f; } hv; hv.u = ((unsigned)h) << 16;
    l = f2bf(x - hv.f);
}

// ---------------------------------------------------------------------------
// Kernel 0: codebooks -> packed hi/lo bf16 MFMA-B-fragment stream:
//   Bp[half][cq(4)][step s=kc*8+nt][{hi 1KB, lo 1KB}], frag elem:
//   n = cq*128 + nt*16 + (lane&15), k = kc*32 + (lane>>4)*8 + j
// ---------------------------------------------------------------------------
__global__ __launch_bounds__(256)
void cvt_bfrag(const float* __restrict__ cb1, const float* __restrict__ cb2,
               char* __restrict__ Bp)
{
    int fid  = blockIdx.x * 256 + threadIdx.x;   // 0..65535
    int lane = fid & 63;
    int nt   = (fid >> 6) & 7;
    int kc   = (fid >> 9) & 15;
    int cq   = (fid >> 13) & 3;
    int hf   = (fid >> 15) & 1;
    const float* cb = hf ? cb2 : cb1;
    int n  = cq * 128 + nt * 16 + (lane & 15);
    int kb = kc * 32 + (lane >> 4) * 8;
    const float* src = cb + (size_t)n * KDIM + kb;
    float4 f0 = *(const float4*)src;
    float4 f1 = *(const float4*)(src + 4);
    unsigned short hh[8], ll[8];
    split_bf(f0.x, hh[0], ll[0]); split_bf(f0.y, hh[1], ll[1]);
    split_bf(f0.z, hh[2], ll[2]); split_bf(f0.w, hh[3], ll[3]);
    split_bf(f1.x, hh[4], ll[4]); split_bf(f1.y, hh[5], ll[5]);
    split_bf(f1.z, hh[6], ll[6]); split_bf(f1.w, hh[7], ll[7]);
    size_t dst = ((size_t)(hf * 4 + cq) * 128 + (kc * 8 + nt)) * 2048 + lane * 16;
    *(int4*)(Bp + dst)        = *(const int4*)hh;
    *(int4*)(Bp + dst + 1024) = *(const int4*)ll;
}

// ---------------------------------------------------------------------------
// Kernel 1: 256 threads (4 waves), 32 tokens, one half. Wave = cand quarter.
//   A: fp32->bf16 hi/lo in 64 KB swizzled LDS (2 token-groups of 16).
//   B: packed hi/lo stream global->register, 8-deep ring; each B fragment
//      feeds 6 MFMAs (2 token-groups x 3 split terms) -> 1 GB L2 traffic.
//   Phase 2: gated ballot-bisect top-8 + rare fp64 slow path (proven).
// ---------------------------------------------------------------------------
__global__ __launch_bounds__(256, 2)
void score_topk_mfma(const float* __restrict__ query,
                     const float* __restrict__ cb1f,
                     const float* __restrict__ cb2f,
                     const char* __restrict__ Bp,
                     int*   __restrict__ tk_idx,
                     float* __restrict__ tk_val)
{
    __shared__ char smem[65536];
    char* sAh = smem;            // bf16 [32][512] swizzled (16B chunks XOR row&7)
    char* sAl = smem + 32768;
    float* sS = (float*)smem;    // phase 2: fp32 [32][512] overlays A

    const int tid  = threadIdx.x;
    const int hf   = blockIdx.y;
    const int tok0 = blockIdx.x * TMB;
    const float* __restrict__ cbf = hf ? cb2f : cb1f;
    const int qoff = hf * HALF;

    const int lane = tid & 63;
    const int wid  = tid >> 6;          // 0..3 = cand quarter
    const int l15  = lane & 15;
    const int lh   = lane >> 4;
    const int l7   = lane & 7;

    // ---- stage A: 32 tok x 512 k fp32 -> bf16 hi/lo, swizzled LDS ----
    #pragma unroll
    for (int i = 0; i < 8; i++) {
        int c   = i * 256 + tid;        // 0..2047 16B-chunks
        int row = c >> 6;
        int b8  = c & 63;
        const float* src = query + (size_t)(tok0 + row) * DDIM + qoff + b8 * 8;
        float4 f0 = *(const float4*)(src);
        float4 f1 = *(const float4*)(src + 4);
        unsigned short hh[8], ll[8];
        split_bf(f0.x, hh[0], ll[0]); split_bf(f0.y, hh[1], ll[1]);
        split_bf(f0.z, hh[2], ll[2]); split_bf(f0.w, hh[3], ll[3]);
        split_bf(f1.x, hh[4], ll[4]); split_bf(f1.y, hh[5], ll[5]);
        split_bf(f1.z, hh[6], ll[6]); split_bf(f1.w, hh[7], ll[7]);
        int boff = row * 1024 + ((b8 * 16) ^ ((row & 7) << 4));
        *(int4*)(sAh + boff) = *(const int4*)hh;
        *(int4*)(sAl + boff) = *(const int4*)ll;
    }
    __syncthreads();

    // ---- B stream: 128 steps (16 kc x 8 nt), 8-deep register ring ----
    const char* bp = Bp + (size_t)(hf * 4 + wid) * 262144 + lane * 16;

    int4 rh[8], rl[8];
    #pragma unroll
    for (int p = 0; p < 8; p++) {
        rh[p] = *(const int4*)(bp + p * 2048);
        rl[p] = *(const int4*)(bp + p * 2048 + 1024);
    }

    f32x4 acc[2][8];
    #pragma unroll
    for (int tg = 0; tg < 2; tg++)
        #pragma unroll
        for (int nt = 0; nt < 8; nt++) acc[tg][nt] = (f32x4){0.f, 0.f, 0.f, 0.f};

    for (int kc = 0; kc < 16; kc++) {
        const int co = (kc * 64 + lh * 16) ^ (l7 << 4);
        const bf16x8 ah0 = *(const bf16x8*)(sAh + l15 * 1024 + co);
        const bf16x8 al0 = *(const bf16x8*)(sAl + l15 * 1024 + co);
        const bf16x8 ah1 = *(const bf16x8*)(sAh + (16 + l15) * 1024 + co);
        const bf16x8 al1 = *(const bf16x8*)(sAl + (16 + l15) * 1024 + co);
        #pragma unroll
        for (int nt = 0; nt < 8; nt++) {
            union { int4 i; bf16x8 b; } ubh, ubl;
            ubh.i = rh[nt]; ubl.i = rl[nt];
            const int sp = (kc * 8 + nt + 8) & 127;
            rh[nt] = *(const int4*)(bp + sp * 2048);
            rl[nt] = *(const int4*)(bp + sp * 2048 + 1024);
            acc[0][nt] = __builtin_amdgcn_mfma_f32_16x16x32_bf16(ah0, ubh.b, acc[0][nt], 0, 0, 0);
            acc[0][nt] = __builtin_amdgcn_mfma_f32_16x16x32_bf16(al0, ubh.b, acc[0][nt], 0, 0, 0);
            acc[0][nt] = __builtin_amdgcn_mfma_f32_16x16x32_bf16(ah0, ubl.b, acc[0][nt], 0, 0, 0);
            acc[1][nt] = __builtin_amdgcn_mfma_f32_16x16x32_bf16(ah1, ubh.b, acc[1][nt], 0, 0, 0);
            acc[1][nt] = __builtin_amdgcn_mfma_f32_16x16x32_bf16(al1, ubh.b, acc[1][nt], 0, 0, 0);
            acc[1][nt] = __builtin_amdgcn_mfma_f32_16x16x32_bf16(ah1, ubl.b, acc[1][nt], 0, 0, 0);
        }
    }
    __syncthreads();   // all A reads done; sS may overwrite sA

    // ---- dump scores: C/D layout row=(lane>>4)*4+r (token), col=lane&15 ----
    #pragma unroll
    for (int tg = 0; tg < 2; tg++)
        #pragma unroll
        for (int nt = 0; nt < 8; nt++)
            #pragma unroll
            for (int r = 0; r < 4; r++) {
                int t = tg * 16 + lh * 4 + r;
                int c = wid * 128 + nt * 16 + l15;
                sS[t * SUB + (c ^ (lh << 3))] = acc[tg][nt][r];  // hash=((t>>2)&3)<<3
            }
    __syncthreads();

    // ---- phase 2: per wave, 8 tokens ----
    for (int v = 0; v < 8; v++) {
        const int t   = wid * 8 + v;
        const int tok = tok0 + t;
        const int hsh = ((t >> 2) & 3) << 3;

        float sv[8];
        #pragma unroll
        for (int j = 0; j < 8; j++) sv[j] = sS[t * SUB + ((lane + 64 * j) ^ hsh)];

        float m = sv[0];
        #pragma unroll
        for (int j = 1; j < 8; j++) m = fmaxf(m, sv[j]);
        #pragma unroll
        for (int off = 32; off > 0; off >>= 1) m = fmaxf(m, __shfl_xor(m, off));

        auto wave_cnt = [&](float tau) -> int {
            int c = 0;
            #pragma unroll
            for (int j = 0; j < 8; j++)
                c += __popcll(__ballot(sv[j] > tau));
            return c;
        };

        float lo = m - 0.5f, hi = m;
        while (wave_cnt(lo) < 9) lo -= 0.5f;
        for (int it = 0; it < 14; it++) {
            float mid = 0.5f * (lo + hi);
            if (wave_cnt(mid) >= 9) lo = mid; else hi = mid;
        }
        int ch8 = wave_cnt(hi);

        float v8 = 1e30f, v9 = -1e30f;
        #pragma unroll
        for (int j = 0; j < 8; j++) {
            bool sel = sv[j] > hi;
            v8 = sel ? fminf(v8, sv[j]) : v8;
            v9 = sel ? v9 : fmaxf(v9, sv[j]);
        }
        #pragma unroll
        for (int off = 32; off > 0; off >>= 1) {
            v8 = fminf(v8, __shfl_xor(v8, off));
            v9 = fmaxf(v9, __shfl_xor(v9, off));
        }

        if (ch8 == 8 && (v8 - v9) > 6e-5f) {
            int base = 0;
            #pragma unroll
            for (int j = 0; j < 8; j++) {
                unsigned long long mk = __ballot(sv[j] > hi);
                if (sv[j] > hi) {
                    int pos = base + __popcll(mk & ((1ULL << lane) - 1ULL));
                    tk_idx[((size_t)tok * 2 + hf) * TOPK + pos] = lane + 64 * j;
                    tk_val[((size_t)tok * 2 + hf) * TOPK + pos] = sv[j];
                }
                base += __popcll(mk);
            }
        } else {
            // slow path (rare): coarse top-16 + fp64 rescore, exact ordering
            int cand[NCAND];
            #pragma unroll
            for (int r = 0; r < NCAND; r++) {
                float bv = sv[0]; int bj = 0;
                #pragma unroll
                for (int j = 1; j < 8; j++) if (sv[j] > bv) { bv = sv[j]; bj = j; }
                int bidx = lane + 64 * bj;
                #pragma unroll
                for (int off = 32; off > 0; off >>= 1) {
                    float ov = __shfl_xor(bv, off);
                    int   oi = __shfl_xor(bidx, off);
                    if (ov > bv || (ov == bv && oi < bidx)) { bv = ov; bidx = oi; }
                }
                cand[r] = bidx;
                int jj = bidx >> 6;
                if ((bidx & 63) == lane) {
                    #pragma unroll
                    for (int j = 0; j < 8; j++) if (j == jj) sv[j] = -INFINITY;
                }
            }
            double qd[8];
            #pragma unroll
            for (int j = 0; j < 8; j++)
                qd[j] = (double)query[(size_t)tok * DDIM + qoff + lane + 64 * j];
            double rv[NCAND];
            #pragma unroll
            for (int r = 0; r < NCAND; r++) {
                const float* __restrict__ crow = &cbf[(size_t)cand[r] * KDIM];
                double a = 0.0;
                #pragma unroll
                for (int j = 0; j < 8; j++)
                    a = fma(qd[j], (double)crow[lane + 64 * j], a);
                #pragma unroll
                for (int off = 32; off > 0; off >>= 1)
                    a += __shfl_xor(a, off);
                rv[r] = a;
            }
            if (lane == 0) {
                #pragma unroll
                for (int r = 0; r < NCAND; r++) {
                    int rk = 0;
                    #pragma unroll
                    for (int mm = 0; mm < NCAND; mm++)
                        if (rv[mm] > rv[r] || (rv[mm] == rv[r] && cand[mm] < cand[r])) rk++;
                    if (rk < TOPK) {
                        tk_idx[((size_t)tok * 2 + hf) * TOPK + rk] = cand[r];
                        tk_val[((size_t)tok * 2 + hf) * TOPK + rk] = (float)rv[r];
                    }
                }
            }
        }
    }
}

// ---------------------------------------------------------------------------
// Kernel 2: one wave per token. softmax(8)x2 -> 64 weighted value rows.
// ---------------------------------------------------------------------------
__global__ __launch_bounds__(256)
void gather_kernel(const float* __restrict__ values,
                   const int*   __restrict__ tk_idx,
                   const float* __restrict__ tk_val,
                   float* __restrict__ out)
{
    const int tid  = threadIdx.x;
    const int lane = tid & 63;
    const int tok  = blockIdx.x * 4 + (tid >> 6);

    const int b1 = (tok * 2 + 0) * TOPK;
    const int b2 = (tok * 2 + 1) * TOPK;

    float v1[8], v2[8]; int i1[8], i2[8];
    #pragma unroll
    for (int j = 0; j < 8; j++) {
        i1[j] = tk_idx[b1 + j]; v1[j] = tk_val[b1 + j];
        i2[j] = tk_idx[b2 + j]; v2[j] = tk_val[b2 + j];
    }

    float m1 = v1[0], m2 = v2[0];
    #pragma unroll
    for (int j = 1; j < 8; j++) { m1 = fmaxf(m1, v1[j]); m2 = fmaxf(m2, v2[j]); }

    float w1[8], w2[8], s1 = 0.f, s2 = 0.f;
    #pragma unroll
    for (int j = 0; j < 8; j++) {
        w1[j] = expf(v1[j] - m1); s1 += w1[j];
        w2[j] = expf(v2[j] - m2); s2 += w2[j];
    }
    const float inv1 = 1.f / s1, inv2 = 1.f / s2;
    #pragma unroll
    for (int j = 0; j < 8; j++) { w1[j] *= inv1; w2[j] *= inv2; }

    float2 acc = make_float2(0.f, 0.f);
    #pragma unroll
    for (int i = 0; i < 8; i++) {
        const int rb = i1[i] * SUB;
        const float wi = w1[i];
        #pragma unroll
        for (int j = 0; j < 8; j++) {
            const float w = wi * w2[j];
            const float* __restrict__ row = values + (size_t)(rb + i2[j]) * VDIM;
            float2 tv = *(const float2*)&row[lane * 2];
            acc.x = fmaf(w, tv.x, acc.x);
            acc.y = fmaf(w, tv.y, acc.y);
        }
    }
    *(float2*)&out[(size_t)tok * VDIM + lane * 2] = acc;
}

extern "C" void kernel_launch(void* const* d_in, const int* in_sizes, int n_in,
                              void* d_out, int out_size, void* d_ws, size_t ws_size,
                              hipStream_t stream) {
    const float* query  = (const float*)d_in[0];
    const float* cb1    = (const float*)d_in[1];
    const float* cb2    = (const float*)d_in[2];
    const float* values = (const float*)d_in[3];
    float* out = (float*)d_out;

    char* ws = (char*)d_ws;
    int*   tk_idx = (int*)ws;                    // 1 MB
    float* tk_val = (float*)(ws + (1u << 20));   // 1 MB
    char*  Bp     = ws + (2u << 20);             // 2 MB packed hi/lo B stream

    cvt_bfrag<<<256, 256, 0, stream>>>(cb1, cb2, Bp);
    dim3 g1(NTOK / TMB, 2);
    score_topk_mfma<<<g1, 256, 0, stream>>>(query, cb1, cb2, Bp, tk_idx, tk_val);
    gather_kernel<<<NTOK / 4, 256, 0, stream>>>(values, tk_idx, tk_val, out);
}